// Round 7
// baseline (232.448 us; speedup 1.0000x reference)
//
#include <hip/hip_runtime.h>
#include <hip/hip_bf16.h>

#define NPIX 36864   // 192*192

typedef __attribute__((ext_vector_type(8))) short short8;
typedef __attribute__((ext_vector_type(4))) short short4v;
typedef __attribute__((ext_vector_type(4))) float float4v;

__device__ inline unsigned short f2b(float x) {
    return __builtin_bit_cast(unsigned short, __float2bfloat16(x));
}
__device__ inline float b2f(unsigned short h) {
    return __uint_as_float(((unsigned int)h) << 16);
}

// ---------------------------------------------------------------- fused weight-prep + x cast
//  wb layout (shorts):
//  [0      ) dw_w2 [256][64]        n=16384
//  [16384  ) pw_w2 [256][64]        n=16384
//  [32768  ) dw_w3 [576][256]       n=147456   } combined [768][256]
//  [180224 ) pw_w3 [192][256]       n=49152    }
//  [229376 ) sigW1t [9][64][64]     n=36864   (tap-major)
//  [266240 ) sigW2t [9][64][64]     n=36864
//  [303104 ) sigW3t [9][16][64]     n=9216    (oc padded 2->16 with zeros)
#define WB_TOTAL 312320
#define XCAST_N  1179648   // 2*64*9216
__global__ __launch_bounds__(256) void prep_all(
    const float* __restrict__ dw2, const float* __restrict__ dw3,
    const float* __restrict__ pw2, const float* __restrict__ pw3,
    const float* __restrict__ sw1, const float* __restrict__ sw2,
    const float* __restrict__ sw3, unsigned short* __restrict__ wb,
    const float* __restrict__ x, unsigned short* __restrict__ xb)
{
    int i = blockIdx.x * 256 + threadIdx.x;
    if (i >= WB_TOTAL) {
        int j = i - WB_TOTAL;
        if (j < XCAST_N) xb[j] = f2b(x[j]);
        return;
    }
    unsigned short v;
    if (i < 16384)        v = f2b(dw2[i]);
    else if (i < 32768)   v = f2b(pw2[i - 16384]);
    else if (i < 180224)  v = f2b(dw3[i - 32768]);
    else if (i < 229376)  v = f2b(pw3[i - 180224]);
    else if (i < 266240) { int j = i - 229376; int t = j / 4096, r = j % 4096, oc = r / 64, ic = r % 64;
                           v = f2b(sw1[(oc * 64 + ic) * 9 + t]); }
    else if (i < 303104) { int j = i - 266240; int t = j / 4096, r = j % 4096, oc = r / 64, ic = r % 64;
                           v = f2b(sw2[(oc * 64 + ic) * 9 + t]); }
    else                 { int j = i - 303104; int t = j / 1024, r = j % 1024, oc = r / 64, ic = r % 64;
                           v = (oc < 2) ? f2b(sw3[(oc * 64 + ic) * 9 + t]) : (unsigned short)0; }
    wb[i] = v;
}

// ---------------------------------------------------------------- fused MLP chain, persistent-LDS weights
// grid (64, 4) x 512 threads = 256 blocks = 1/CU, 8 waves = 2/SIMD.
// R7: barrier-drain reduction. Each __syncthreads compiles to s_waitcnt vmcnt(0) lgkmcnt(0)
// + s_barrier; R6 had 6/tile (54 total), each draining in-flight global stores/loads.
// Now 2/tile (18 total):
//   - h1s de-aliased from h2s (own 8 KB; LDS 139264 <= 160K) -> barrier B gone.
//   - epilogue stores DIRECTLY from acc registers (24 ushort stores/lane/tile; 16-lane
//     32 B segments, L2 merges with the paired nh-wave) -> Ts + barriers D/E/F gone.
//     Ordering of L3-reads(t) vs pack-writes(t+1) is carried transitively by A(t+1).
//   - all loop-invariant scalars hoisted (w1 rows, b1/b2/b3 biases -> ~52 VGPR).
// Per tile: L1 -> A -> bv-read, L2+pack -> C -> L3 + reg-stores.
// LDS 139264 B: Ws [0,98304); h2s [98304,131072); h1s [131072,139264).
__global__ __launch_bounds__(512, 2) void mlp_fused(
    const float* __restrict__ pose,
    const float* __restrict__ w1A, const float* __restrict__ b1A,
    const float* __restrict__ w1B, const float* __restrict__ b1B,
    const unsigned short* __restrict__ w2A, const unsigned short* __restrict__ w2B,
    const float* __restrict__ b2A, const float* __restrict__ b2B,
    const unsigned short* __restrict__ w33,
    const float* __restrict__ b3A, const float* __restrict__ b3B,
    unsigned short* __restrict__ outA, unsigned short* __restrict__ outB)
{
    __shared__ unsigned short sh[69632];          // 139264 B
    unsigned short* Ws  = sh;                     // 98304 B
    unsigned short* h2s = sh + 49152;             // 32768 B
    unsigned short* h1s = sh + 65536;             // 8192 B (no alias)
    const int tid = threadIdx.x;
    const int u = blockIdx.y;                    // 0..3
    const int chain = (u == 3) ? 1 : 0;
    const int w = tid >> 6, l = tid & 63;        // w 0..7
    const int ln = l & 15, lkg = l >> 4, lk = lkg * 8;
    const float* w1 = chain ? w1B : w1A;
    const float* b1 = chain ? b1B : b1A;
    const unsigned short* w2 = chain ? w2B : w2A;
    const float* b2 = chain ? b2B : b2A;
    const int rowbase = chain ? 576 : u * 192;   // row into w33
    const int obase   = chain ? 0 : u * 192;     // row into output
    const float* b3 = chain ? b3B : b3A;
    unsigned short* outp = chain ? outB : outA;

    // ---- stage full 192x256 w33 slice into Ws (once). Linear LDS dest, pre-swizzled
    //      global source: LDS[a] = Wlin[a ^ ((a>>9)&7)<<4] (involution on bits 4-6).
    for (int i = 0; i < 12; ++i) {
        const int chunk = (i * 8 + w) * 1024;    // per-wave 1024 B
        int a  = chunk + l * 16;
        int ap = a ^ (((a >> 9) & 7) << 4);
        const unsigned short* gp =
            &w33[(size_t)(rowbase + (ap >> 9)) * 256 + ((ap & 511) >> 1)];
        __builtin_amdgcn_global_load_lds(
            (const __attribute__((address_space(1))) void*)gp,
            (__attribute__((address_space(3))) void*)((char*)Ws + chunk),
            16, 0, 0);
    }
    // ---- hoist w2 fragments (16 VGPR, loop-invariant)
    short8 Aw2[2][2];
    #pragma unroll
    for (int mt = 0; mt < 2; ++mt) {
        int ocr = w * 32 + mt * 16 + ln;
        Aw2[mt][0] = *(const short8*)&w2[(size_t)ocr * 64 + lk];
        Aw2[mt][1] = *(const short8*)&w2[(size_t)ocr * 64 + 32 + lk];
    }
    // ---- hoist L1 weights/biases (32 VGPR) - identical every tile
    float w1r[8][3], b1r[8];
    #pragma unroll
    for (int j = 0; j < 8; ++j) {
        int oc = w * 8 + j;
        w1r[j][0] = w1[oc * 3]; w1r[j][1] = w1[oc * 3 + 1]; w1r[j][2] = w1[oc * 3 + 2];
        b1r[j] = b1[oc];
    }
    // ---- hoist L2 pack biases (8 VGPR)
    float b2r[2][4];
    #pragma unroll
    for (int mt = 0; mt < 2; ++mt) {
        int ocb = w * 32 + mt * 16 + lkg * 4;
        #pragma unroll
        for (int r = 0; r < 4; ++r) b2r[mt][r] = b2[ocb + r];
    }
    // ---- L3 wave task split + hoisted L3 biases (12 VGPR)
    const int nh = w & 1, mb = w >> 1;
    float b3r[3][4];
    #pragma unroll
    for (int s = 0; s < 3; ++s) {
        int tr0 = (mb + s * 4) * 16 + lkg * 4;
        #pragma unroll
        for (int r = 0; r < 4; ++r) b3r[s][r] = b3[obase + tr0 + r];
    }
    // ---- pose preload for tile 0
    const int pxbase = blockIdx.x * 576;
    float p0 = pose[pxbase + l], p1 = pose[NPIX + pxbase + l], p2 = pose[2 * NPIX + pxbase + l];

    for (int it = 0; it < 9; ++it) {
        const int px0 = pxbase + it * 64;
        // ---- layer 1: 3 -> 64, pure register FMA; one packed b128 store
        {
            short8 s0;
            #pragma unroll
            for (int j = 0; j < 8; ++j) {
                float v = b1r[j] + w1r[j][0] * p0 + w1r[j][1] * p1 + w1r[j][2] * p2;
                s0[j] = (short)f2b(fmaxf(v, 0.f));
            }
            *(short8*)&h1s[w * 512 + l * 8] = s0;
        }
        // ---- prefetch next tile's pose
        float np0 = 0.f, np1 = 0.f, np2 = 0.f;
        if (it < 8) {
            int pxn = px0 + 64 + l;
            np0 = pose[pxn]; np1 = pose[NPIX + pxn]; np2 = pose[2 * NPIX + pxn];
        }
        __syncthreads();   // A: h1s ready (tile 0: also drains Ws staging);
                           //    transitively orders L3-reads(t-1) before pack-writes(t)
        // ---- layer 2: b-fragments from h1s (disjoint from h2s -> no extra barrier), MFMA, pack
        {
            short8 b0v[4], b1v[4];
            #pragma unroll
            for (int nt = 0; nt < 4; ++nt) {
                b0v[nt] = *(const short8*)&h1s[(lkg    ) * 512 + (nt * 16 + ln) * 8];
                b1v[nt] = *(const short8*)&h1s[(4 + lkg) * 512 + (nt * 16 + ln) * 8];
            }
            float4v acc2[2][4] = {};
            #pragma unroll
            for (int mt = 0; mt < 2; ++mt) {
                #pragma unroll
                for (int nt = 0; nt < 4; ++nt) {
                    acc2[mt][nt] = __builtin_amdgcn_mfma_f32_16x16x32_bf16(Aw2[mt][0], b0v[nt], acc2[mt][nt], 0, 0, 0);
                    acc2[mt][nt] = __builtin_amdgcn_mfma_f32_16x16x32_bf16(Aw2[mt][1], b1v[nt], acc2[mt][nt], 0, 0, 0);
                }
            }
            #pragma unroll
            for (int mt = 0; mt < 2; ++mt) {
                int ocb = w * 32 + mt * 16 + lkg * 4;
                int chk = ocb >> 3, pos = (lkg & 1) * 4;
                #pragma unroll
                for (int nt = 0; nt < 4; ++nt) {
                    int pxl = nt * 16 + ln;
                    short4v pk;
                    pk[0] = (short)f2b(fmaxf(acc2[mt][nt][0] + b2r[mt][0], 0.f));
                    pk[1] = (short)f2b(fmaxf(acc2[mt][nt][1] + b2r[mt][1], 0.f));
                    pk[2] = (short)f2b(fmaxf(acc2[mt][nt][2] + b2r[mt][2], 0.f));
                    pk[3] = (short)f2b(fmaxf(acc2[mt][nt][3] + b2r[mt][3], 0.f));
                    *(short4v*)&h2s[chk * 512 + pxl * 8 + pos] = pk;
                }
            }
        }
        __syncthreads();   // C: h2s ready
        // ---- layer 3: wave computes 3 m-groups x 1 n-half from resident Ws
        float4v acc[3][2] = {};
        {
            const int r0l = mb * 16 + ln;
            const int swz = (r0l & 7) << 4;
            const char* Wb = (const char*)Ws;
            #pragma unroll
            for (int kc = 0; kc < 8; ++kc) {
                short8 a0 = *(const short8*)(Wb + (((r0l      ) * 512 + kc * 64 + lk * 2) ^ swz));
                short8 a1 = *(const short8*)(Wb + (((r0l +  64) * 512 + kc * 64 + lk * 2) ^ swz));
                short8 a2 = *(const short8*)(Wb + (((r0l + 128) * 512 + kc * 64 + lk * 2) ^ swz));
                #pragma unroll
                for (int ni = 0; ni < 2; ++ni) {
                    int nt = nh * 2 + ni;
                    short8 b = *(const short8*)&h2s[(kc * 4 + lkg) * 512 + (nt * 16 + ln) * 8];
                    acc[0][ni] = __builtin_amdgcn_mfma_f32_16x16x32_bf16(a0, b, acc[0][ni], 0, 0, 0);
                    acc[1][ni] = __builtin_amdgcn_mfma_f32_16x16x32_bf16(a1, b, acc[1][ni], 0, 0, 0);
                    acc[2][ni] = __builtin_amdgcn_mfma_f32_16x16x32_bf16(a2, b, acc[2][ni], 0, 0, 0);
                }
            }
        }
        // ---- epilogue: bias + direct register stores (no LDS transpose, no barrier;
        //      stores drain lazily at A(t+1))
        #pragma unroll
        for (int s = 0; s < 3; ++s) {
            const int tr0 = (mb + s * 4) * 16 + lkg * 4;
            #pragma unroll
            for (int r = 0; r < 4; ++r) {
                const size_t rowoff = (size_t)(obase + tr0 + r) * NPIX + px0;
                #pragma unroll
                for (int ni = 0; ni < 2; ++ni) {
                    int px = nh * 32 + ni * 16 + ln;
                    outp[rowoff + px] = f2b(acc[s][ni][r] + b3r[s][r]);
                }
            }
        }
        p0 = np0; p1 = np1; p2 = np2;
    }
}

// ---------------------------------------------------------------- bf16 MFMA 3x3 conv, 2-row tiles
template<int MT>
__global__ __launch_bounds__(256) void conv3x3_mfma(
    const unsigned short* __restrict__ act, const unsigned short* __restrict__ wgt,
    const float* __restrict__ bias, unsigned short* __restrict__ out,
    int relu)
{
    constexpr int SP = 72;
    constexpr int OCP = MT * 16;
    __shared__ unsigned short Bs[4 * 66 * SP];   // 38016 B
    const int tid = threadIdx.x;
    int bx = blockIdx.x;
    const int xt = bx % 3; bx /= 3;
    const int yg = bx % 96; const int b = bx / 96;
    const int y0 = yg * 2;
    const int x0 = xt * 64;
    const size_t actb = (size_t)b * NPIX * 64;
    const int w = tid >> 6, l = tid & 63;
    const int ln = l & 15, lkg = l >> 4, lk = lkg * 8;
    const int mt = (MT == 4) ? w : 0;
    short8 Wr[9][2];
    #pragma unroll
    for (int t = 0; t < 9; ++t)
        #pragma unroll
        for (int hh = 0; hh < 2; ++hh)
            Wr[t][hh] = *(const short8*)&wgt[((size_t)t * OCP + mt * 16 + ln) * 64 + hh * 32 + lk];
    for (int s = tid; s < 264; s += 256) {
        int r = s / 66, i = s % 66;
        int yy = y0 + r - 1, xx = x0 + i - 1;
        unsigned short* dst = &Bs[(r * 66 + i) * SP];
        if (yy >= 0 && yy < 192 && xx >= 0 && xx < 192) {
            const unsigned short* src = &act[actb + (size_t)(yy * 192 + xx) * 64];
            #pragma unroll
            for (int j = 0; j < 8; ++j) *(short8*)(dst + j * 8) = *(const short8*)(src + j * 8);
        } else {
            short8 z = {};
            #pragma unroll
            for (int j = 0; j < 8; ++j) *(short8*)(dst + j * 8) = z;
        }
    }
    __syncthreads();
    const int NT = (MT == 4) ? 4 : 1;
    const int ntb = (MT == 4) ? 0 : w;
    float4v acc[2][4] = {};
    #pragma unroll
    for (int t = 0; t < 9; ++t) {
        const int r = t / 3, dx = t % 3;
        #pragma unroll
        for (int hh = 0; hh < 2; ++hh) {
            #pragma unroll
            for (int o = 0; o < 2; ++o) {
                #pragma unroll
                for (int n = 0; n < 4; ++n) {
                    if (n >= NT) break;
                    int slot = (o + r) * 66 + (ntb + n) * 16 + ln + dx;
                    short8 bf = *(const short8*)&Bs[slot * SP + hh * 32 + lk];
                    acc[o][n] = __builtin_amdgcn_mfma_f32_16x16x32_bf16(Wr[t][hh], bf, acc[o][n], 0, 0, 0);
                }
            }
        }
    }
    #pragma unroll
    for (int o = 0; o < 2; ++o) {
        #pragma unroll
        for (int n = 0; n < 4; ++n) {
            if (n >= NT) break;
            int px = (y0 + o) * 192 + x0 + (ntb + n) * 16 + ln;
            if (MT == 4) {
                int oc = mt * 16 + lkg * 4;
                float v0 = acc[o][n][0] + bias[oc + 0];
                float v1 = acc[o][n][1] + bias[oc + 1];
                float v2 = acc[o][n][2] + bias[oc + 2];
                float v3 = acc[o][n][3] + bias[oc + 3];
                if (relu) { v0 = fmaxf(v0, 0.f); v1 = fmaxf(v1, 0.f); v2 = fmaxf(v2, 0.f); v3 = fmaxf(v3, 0.f); }
                uint2 pk;
                pk.x = (unsigned int)f2b(v0) | (((unsigned int)f2b(v1)) << 16);
                pk.y = (unsigned int)f2b(v2) | (((unsigned int)f2b(v3)) << 16);
                *(uint2*)&out[((size_t)b * NPIX + px) * 64 + oc] = pk;
            } else if (lkg == 0) {
                float v0 = acc[o][n][0] + bias[0];
                float v1 = acc[o][n][1] + bias[1];
                out[((size_t)b * 2 + 0) * NPIX + px] = f2b(v0);
                out[((size_t)b * 2 + 1) * NPIX + px] = f2b(v1);
            }
        }
    }
}

// ---------------------------------------------------------------- mean: single-plane LDS, sequential b
// LDS 20.4 KB -> 7 blocks/CU. b-invariant softmax weights precomputed in registers.
#define PLSZ 10192   // 98*104
__global__ __launch_bounds__(256) void mean_k(
    const unsigned short* __restrict__ xb, const int* __restrict__ imy, const int* __restrict__ imx,
    const unsigned short* __restrict__ dw, unsigned short* __restrict__ mean_cm)
{
    __shared__ unsigned short pl[PLSZ];
    const int c = blockIdx.y;
    const int px0 = blockIdx.x * 1024;
    const int tid = threadIdx.x;
    {   // zero once; borders stay zero across both stages (restage touches interior only)
        short8 z = {};
        short8* pf = (short8*)pl;
        for (int i = tid; i < PLSZ / 8; i += 256) pf[i] = z;
    }
    float wk[4][9];
    int base[4];
    #pragma unroll
    for (int q = 0; q < 4; ++q) {
        int px = px0 + q * 256 + tid;
        base[q] = imy[px] * 104 + imx[px] + 3;
        float d[9];
        #pragma unroll
        for (int k = 0; k < 9; ++k) d[k] = b2f(dw[(size_t)(c * 9 + k) * NPIX + px]);
        float m = d[0];
        #pragma unroll
        for (int k = 1; k < 9; ++k) m = fmaxf(m, d[k]);
        float s = 0.f;
        #pragma unroll
        for (int k = 0; k < 9; ++k) { wk[q][k] = __expf(d[k] - m); s += wk[q][k]; }
        float inv = 1.f / s;
        #pragma unroll
        for (int k = 0; k < 9; ++k) wk[q][k] *= inv;
    }
    #pragma unroll
    for (int b = 0; b < 2; ++b) {
        __syncthreads();   // zero done (b=0) / prior reads done (b=1)
        const unsigned short* xp = xb + (size_t)(b * 64 + c) * 9216;
        for (int i = tid; i < 96 * 12; i += 256) {
            int row = i / 12, ch = i % 12;
            const short4v* src = (const short4v*)&xp[row * 96 + ch * 8];
            unsigned short* dd = &pl[(row + 1) * 104 + 4 + ch * 8];
            *(short4v*)dd = src[0];
            *(short4v*)(dd + 4) = src[1];
        }
        __syncthreads();
        #pragma unroll
        for (int q = 0; q < 4; ++q) {
            int px = px0 + q * 256 + tid;
            float a = 0.f;
            #pragma unroll
            for (int k = 0; k < 9; ++k)
                a += wk[q][k] * b2f(pl[base[q] + (k / 3) * 104 + (k % 3)]);
            mean_cm[(size_t)(b * 64 + c) * NPIX + px] = f2b(a);
        }
    }
}

// ---------------------------------------------------------------- transpose [2][64][NPIX] -> [2][NPIX][64]
__global__ __launch_bounds__(256) void tr_k(
    const unsigned short* __restrict__ in, unsigned short* __restrict__ out)
{
    __shared__ unsigned short T[64 * 68];
    int px0 = blockIdx.x * 64;
    int b = blockIdx.y;
    int tid = threadIdx.x;
    for (int i = tid; i < 4096; i += 256) {
        int c = i >> 6, p = i & 63;
        T[p * 68 + c] = in[(size_t)(b * 64 + c) * NPIX + px0 + p];
    }
    __syncthreads();
    for (int i = tid; i < 4096; i += 256) {
        int p = i >> 6, c = i & 63;
        out[((size_t)b * NPIX + px0 + p) * 64 + c] = T[p * 68 + c];
    }
}

// ---------------------------------------------------------------- xa: single-plane LDS, sequential b
__global__ __launch_bounds__(256) void xa_k(
    const unsigned short* __restrict__ xb, const int* __restrict__ imy, const int* __restrict__ imx,
    const unsigned short* __restrict__ dw, const unsigned short* __restrict__ mean_cm,
    const unsigned short* __restrict__ sigma, unsigned short* __restrict__ xab)
{
    __shared__ unsigned short pl[PLSZ];
    const int c = blockIdx.y;
    const int px0 = blockIdx.x * 1024;
    const int tid = threadIdx.x;
    {
        short8 z = {};
        short8* pf = (short8*)pl;
        for (int i = tid; i < PLSZ / 8; i += 256) pf[i] = z;
    }
    float d[4][9];
    int base[4];
    #pragma unroll
    for (int q = 0; q < 4; ++q) {
        int px = px0 + q * 256 + tid;
        base[q] = imy[px] * 104 + imx[px] + 3;
        #pragma unroll
        for (int k = 0; k < 9; ++k) d[q][k] = b2f(dw[(size_t)(c * 9 + k) * NPIX + px]);
    }
    #pragma unroll
    for (int b = 0; b < 2; ++b) {
        __syncthreads();
        const unsigned short* xp = xb + (size_t)(b * 64 + c) * 9216;
        for (int i = tid; i < 96 * 12; i += 256) {
            int row = i / 12, ch = i % 12;
            const short4v* src = (const short4v*)&xp[row * 96 + ch * 8];
            unsigned short* dd = &pl[(row + 1) * 104 + 4 + ch * 8];
            *(short4v*)dd = src[0];
            *(short4v*)(dd + 4) = src[1];
        }
        __syncthreads();
        #pragma unroll
        for (int q = 0; q < 4; ++q) {
            int px = px0 + q * 256 + tid;
            float mn = b2f(mean_cm[(size_t)(b * 64 + c) * NPIX + px]);
            float sd = b2f(sigma[((size_t)b * 2 + 0) * NPIX + px]);
            float sr = b2f(sigma[((size_t)b * 2 + 1) * NPIX + px]);
            float h[9], bw[9];
            #pragma unroll
            for (int k = 0; k < 9; ++k) {
                h[k] = b2f(pl[base[q] + (k / 3) * 104 + (k % 3)]);
                bw[k] = sd * d[q][k] + sr * fabsf(h[k] - mn);
            }
            float m = bw[0];
            #pragma unroll
            for (int k = 1; k < 9; ++k) m = fmaxf(m, bw[k]);
            float s = 0.f, a = 0.f;
            #pragma unroll
            for (int k = 0; k < 9; ++k) { float e = __expf(bw[k] - m); s += e; a += e * h[k]; }
            xab[(size_t)(b * 64 + c) * NPIX + px] = f2b(a / s);
        }
    }
}

// ---------------------------------------------------------------- fused einsum: block = 64 px, 4 c-quarters
__global__ __launch_bounds__(256) void einsum_k(
    const unsigned short* __restrict__ xab, const unsigned short* __restrict__ pw,
    float* __restrict__ out)
{
    __shared__ float red[3][4][64];
    const int tid = threadIdx.x;
    const int pxl = tid & 63, cq = tid >> 6;
    const int px = blockIdx.x * 64 + pxl;
    const int b = blockIdx.y;
    float a0 = 0.f, a1 = 0.f, a2 = 0.f;
    #pragma unroll
    for (int ci = 0; ci < 16; ++ci) {
        int c = cq * 16 + ci;
        float v = b2f(xab[(size_t)(b * 64 + c) * NPIX + px]);
        a0 += v * b2f(pw[(size_t)(c * 3 + 0) * NPIX + px]);
        a1 += v * b2f(pw[(size_t)(c * 3 + 1) * NPIX + px]);
        a2 += v * b2f(pw[(size_t)(c * 3 + 2) * NPIX + px]);
    }
    red[0][cq][pxl] = a0;
    red[1][cq][pxl] = a1;
    red[2][cq][pxl] = a2;
    __syncthreads();
    if (cq < 3) {
        float s = red[cq][0][pxl] + red[cq][1][pxl] + red[cq][2][pxl] + red[cq][3][pxl];
        out[((size_t)b * 3 + cq) * NPIX + px] = s;
    }
}

extern "C" void kernel_launch(void* const* d_in, const int* in_sizes, int n_in,
                              void* d_out, int out_size, void* d_ws, size_t ws_size,
                              hipStream_t stream)
{
    (void)in_sizes; (void)n_in; (void)out_size; (void)ws_size;
    const float* x      = (const float*)d_in[0];
    const float* pose   = (const float*)d_in[1];
    const int*   imy    = (const int*)d_in[2];
    const int*   imx    = (const int*)d_in[3];
    const float* sig_w1 = (const float*)d_in[4];
    const float* sig_b1 = (const float*)d_in[5];
    const float* sig_w2 = (const float*)d_in[6];
    const float* sig_b2 = (const float*)d_in[7];
    const float* sig_w3 = (const float*)d_in[8];
    const float* sig_b3 = (const float*)d_in[9];
    const float* dw_w1  = (const float*)d_in[10];
    const float* dw_b1  = (const float*)d_in[11];
    const float* dw_w2  = (const float*)d_in[12];
    const float* dw_b2  = (const float*)d_in[13];
    const float* dw_w3  = (const float*)d_in[14];
    const float* dw_b3  = (const float*)d_in[15];
    const float* pw_w1  = (const float*)d_in[16];
    const float* pw_b1  = (const float*)d_in[17];
    const float* pw_w2  = (const float*)d_in[18];
    const float* pw_b2  = (const float*)d_in[19];
    const float* pw_w3  = (const float*)d_in[20];
    const float* pw_b3  = (const float*)d_in[21];
    float* out = (float*)d_out;

    unsigned short* ws = (unsigned short*)d_ws;
    size_t off = 0;
    unsigned short* wb      = ws + off; off += WB_TOTAL;
    unsigned short* xb16    = ws + off; off += (size_t)XCAST_N;
    unsigned short* dwbuf   = ws + off; off += (size_t)576 * NPIX;      // plane-major
    unsigned short* pwbuf   = ws + off; off += (size_t)192 * NPIX;      // plane-major
    unsigned short* mean_cm = ws + off; off += (size_t)2 * 64 * NPIX;
    unsigned short* mean_pm = ws + off; off += (size_t)2 * NPIX * 64;
    unsigned short* s1      = ws + off; off += (size_t)2 * NPIX * 64;
    unsigned short* s2      = ws + off; off += (size_t)2 * NPIX * 64;
    unsigned short* sigma   = ws + off; off += (size_t)2 * 2 * NPIX;
    unsigned short* xab     = ws + off; off += (size_t)2 * 64 * NPIX;

    unsigned short* w_dw2 = wb + 0;
    unsigned short* w_pw2 = wb + 16384;
    unsigned short* w_33  = wb + 32768;   // combined [768][256]
    unsigned short* w_s1t = wb + 229376;
    unsigned short* w_s2t = wb + 266240;
    unsigned short* w_s3t = wb + 303104;

    dim3 blk(256);
    prep_all<<<dim3((WB_TOTAL + XCAST_N + 255) / 256), blk, 0, stream>>>(
        dw_w2, dw_w3, pw_w2, pw_w3, sig_w1, sig_w2, sig_w3, wb, x, xb16);
    mlp_fused<<<dim3(64, 4), dim3(512), 0, stream>>>(
        pose, dw_w1, dw_b1, pw_w1, pw_b1, w_dw2, w_pw2, dw_b2, pw_b2,
        w_33, dw_b3, pw_b3, dwbuf, pwbuf);
    mean_k<<<dim3(36, 64), blk, 0, stream>>>(xb16, imy, imx, dwbuf, mean_cm);
    tr_k<<<dim3(576, 2), blk, 0, stream>>>(mean_cm, mean_pm);
    conv3x3_mfma<4><<<dim3(576), blk, 0, stream>>>(mean_pm, w_s1t, sig_b1, s1, 1);
    conv3x3_mfma<4><<<dim3(576), blk, 0, stream>>>(s1,      w_s2t, sig_b2, s2, 1);
    conv3x3_mfma<1><<<dim3(576), blk, 0, stream>>>(s2,      w_s3t, sig_b3, sigma, 0);
    xa_k<<<dim3(36, 64), blk, 0, stream>>>(xb16, imy, imx, dwbuf, mean_cm, sigma, xab);
    einsum_k<<<dim3(576, 2), blk, 0, stream>>>(xab, pwbuf, out);
}

// Round 8
// 226.540 us; speedup vs baseline: 1.0261x; 1.0261x over previous
//
#include <hip/hip_runtime.h>
#include <hip/hip_bf16.h>

#define NPIX 36864   // 192*192

typedef __attribute__((ext_vector_type(8))) short short8;
typedef __attribute__((ext_vector_type(4))) short short4v;
typedef __attribute__((ext_vector_type(4))) float float4v;

__device__ inline unsigned short f2b(float x) {
    return __builtin_bit_cast(unsigned short, __float2bfloat16(x));
}
__device__ inline float b2f(unsigned short h) {
    return __uint_as_float(((unsigned int)h) << 16);
}

// ---------------------------------------------------------------- fused weight-prep + x cast
//  wb layout (shorts):
//  [0      ) dw_w2 [256][64]        n=16384
//  [16384  ) pw_w2 [256][64]        n=16384
//  [32768  ) dw_w3 [576][256]       n=147456   } combined [768][256]
//  [180224 ) pw_w3 [192][256]       n=49152    }
//  [229376 ) sigW1t [9][64][64]     n=36864   (tap-major)
//  [266240 ) sigW2t [9][64][64]     n=36864
//  [303104 ) sigW3t [9][16][64]     n=9216    (oc padded 2->16 with zeros)
#define WB_TOTAL 312320
#define XCAST_N  1179648   // 2*64*9216
__global__ __launch_bounds__(256) void prep_all(
    const float* __restrict__ dw2, const float* __restrict__ dw3,
    const float* __restrict__ pw2, const float* __restrict__ pw3,
    const float* __restrict__ sw1, const float* __restrict__ sw2,
    const float* __restrict__ sw3, unsigned short* __restrict__ wb,
    const float* __restrict__ x, unsigned short* __restrict__ xb)
{
    int i = blockIdx.x * 256 + threadIdx.x;
    if (i >= WB_TOTAL) {
        int j = i - WB_TOTAL;
        if (j < XCAST_N) xb[j] = f2b(x[j]);
        return;
    }
    unsigned short v;
    if (i < 16384)        v = f2b(dw2[i]);
    else if (i < 32768)   v = f2b(pw2[i - 16384]);
    else if (i < 180224)  v = f2b(dw3[i - 32768]);
    else if (i < 229376)  v = f2b(pw3[i - 180224]);
    else if (i < 266240) { int j = i - 229376; int t = j / 4096, r = j % 4096, oc = r / 64, ic = r % 64;
                           v = f2b(sw1[(oc * 64 + ic) * 9 + t]); }
    else if (i < 303104) { int j = i - 266240; int t = j / 4096, r = j % 4096, oc = r / 64, ic = r % 64;
                           v = f2b(sw2[(oc * 64 + ic) * 9 + t]); }
    else                 { int j = i - 303104; int t = j / 1024, r = j % 1024, oc = r / 64, ic = r % 64;
                           v = (oc < 2) ? f2b(sw3[(oc * 64 + ic) * 9 + t]) : (unsigned short)0; }
    wb[i] = v;
}

// ---------------------------------------------------------------- fused MLP chain, persistent-LDS weights
// grid (64, 4) x 512 threads = 256 blocks = 1/CU, 8 waves = 2/SIMD. (R7 structure, kept.)
// LDS 139264 B: Ws [0,98304); h2s [98304,131072); h1s [131072,139264). 2 barriers/tile.
__global__ __launch_bounds__(512, 2) void mlp_fused(
    const float* __restrict__ pose,
    const float* __restrict__ w1A, const float* __restrict__ b1A,
    const float* __restrict__ w1B, const float* __restrict__ b1B,
    const unsigned short* __restrict__ w2A, const unsigned short* __restrict__ w2B,
    const float* __restrict__ b2A, const float* __restrict__ b2B,
    const unsigned short* __restrict__ w33,
    const float* __restrict__ b3A, const float* __restrict__ b3B,
    unsigned short* __restrict__ outA, unsigned short* __restrict__ outB)
{
    __shared__ unsigned short sh[69632];          // 139264 B
    unsigned short* Ws  = sh;                     // 98304 B
    unsigned short* h2s = sh + 49152;             // 32768 B
    unsigned short* h1s = sh + 65536;             // 8192 B (no alias)
    const int tid = threadIdx.x;
    const int u = blockIdx.y;                    // 0..3
    const int chain = (u == 3) ? 1 : 0;
    const int w = tid >> 6, l = tid & 63;        // w 0..7
    const int ln = l & 15, lkg = l >> 4, lk = lkg * 8;
    const float* w1 = chain ? w1B : w1A;
    const float* b1 = chain ? b1B : b1A;
    const unsigned short* w2 = chain ? w2B : w2A;
    const float* b2 = chain ? b2B : b2A;
    const int rowbase = chain ? 576 : u * 192;   // row into w33
    const int obase   = chain ? 0 : u * 192;     // row into output
    const float* b3 = chain ? b3B : b3A;
    unsigned short* outp = chain ? outB : outA;

    // ---- stage full 192x256 w33 slice into Ws (once). Linear LDS dest, pre-swizzled
    //      global source: LDS[a] = Wlin[a ^ ((a>>9)&7)<<4] (involution on bits 4-6).
    for (int i = 0; i < 12; ++i) {
        const int chunk = (i * 8 + w) * 1024;    // per-wave 1024 B
        int a  = chunk + l * 16;
        int ap = a ^ (((a >> 9) & 7) << 4);
        const unsigned short* gp =
            &w33[(size_t)(rowbase + (ap >> 9)) * 256 + ((ap & 511) >> 1)];
        __builtin_amdgcn_global_load_lds(
            (const __attribute__((address_space(1))) void*)gp,
            (__attribute__((address_space(3))) void*)((char*)Ws + chunk),
            16, 0, 0);
    }
    // ---- hoist w2 fragments (16 VGPR, loop-invariant)
    short8 Aw2[2][2];
    #pragma unroll
    for (int mt = 0; mt < 2; ++mt) {
        int ocr = w * 32 + mt * 16 + ln;
        Aw2[mt][0] = *(const short8*)&w2[(size_t)ocr * 64 + lk];
        Aw2[mt][1] = *(const short8*)&w2[(size_t)ocr * 64 + 32 + lk];
    }
    // ---- hoist L1 weights/biases (32 VGPR) - identical every tile
    float w1r[8][3], b1r[8];
    #pragma unroll
    for (int j = 0; j < 8; ++j) {
        int oc = w * 8 + j;
        w1r[j][0] = w1[oc * 3]; w1r[j][1] = w1[oc * 3 + 1]; w1r[j][2] = w1[oc * 3 + 2];
        b1r[j] = b1[oc];
    }
    // ---- hoist L2 pack biases (8 VGPR)
    float b2r[2][4];
    #pragma unroll
    for (int mt = 0; mt < 2; ++mt) {
        int ocb = w * 32 + mt * 16 + lkg * 4;
        #pragma unroll
        for (int r = 0; r < 4; ++r) b2r[mt][r] = b2[ocb + r];
    }
    // ---- L3 wave task split + hoisted L3 biases (12 VGPR)
    const int nh = w & 1, mb = w >> 1;
    float b3r[3][4];
    #pragma unroll
    for (int s = 0; s < 3; ++s) {
        int tr0 = (mb + s * 4) * 16 + lkg * 4;
        #pragma unroll
        for (int r = 0; r < 4; ++r) b3r[s][r] = b3[obase + tr0 + r];
    }
    // ---- pose preload for tile 0
    const int pxbase = blockIdx.x * 576;
    float p0 = pose[pxbase + l], p1 = pose[NPIX + pxbase + l], p2 = pose[2 * NPIX + pxbase + l];

    for (int it = 0; it < 9; ++it) {
        const int px0 = pxbase + it * 64;
        // ---- layer 1: 3 -> 64, pure register FMA; one packed b128 store
        {
            short8 s0;
            #pragma unroll
            for (int j = 0; j < 8; ++j) {
                float v = b1r[j] + w1r[j][0] * p0 + w1r[j][1] * p1 + w1r[j][2] * p2;
                s0[j] = (short)f2b(fmaxf(v, 0.f));
            }
            *(short8*)&h1s[w * 512 + l * 8] = s0;
        }
        // ---- prefetch next tile's pose
        float np0 = 0.f, np1 = 0.f, np2 = 0.f;
        if (it < 8) {
            int pxn = px0 + 64 + l;
            np0 = pose[pxn]; np1 = pose[NPIX + pxn]; np2 = pose[2 * NPIX + pxn];
        }
        __syncthreads();   // A: h1s ready (tile 0: also drains Ws staging);
                           //    transitively orders L3-reads(t-1) before pack-writes(t)
        // ---- layer 2: b-fragments from h1s (disjoint from h2s -> no extra barrier), MFMA, pack
        {
            short8 b0v[4], b1v[4];
            #pragma unroll
            for (int nt = 0; nt < 4; ++nt) {
                b0v[nt] = *(const short8*)&h1s[(lkg    ) * 512 + (nt * 16 + ln) * 8];
                b1v[nt] = *(const short8*)&h1s[(4 + lkg) * 512 + (nt * 16 + ln) * 8];
            }
            float4v acc2[2][4] = {};
            #pragma unroll
            for (int mt = 0; mt < 2; ++mt) {
                #pragma unroll
                for (int nt = 0; nt < 4; ++nt) {
                    acc2[mt][nt] = __builtin_amdgcn_mfma_f32_16x16x32_bf16(Aw2[mt][0], b0v[nt], acc2[mt][nt], 0, 0, 0);
                    acc2[mt][nt] = __builtin_amdgcn_mfma_f32_16x16x32_bf16(Aw2[mt][1], b1v[nt], acc2[mt][nt], 0, 0, 0);
                }
            }
            #pragma unroll
            for (int mt = 0; mt < 2; ++mt) {
                int ocb = w * 32 + mt * 16 + lkg * 4;
                int chk = ocb >> 3, pos = (lkg & 1) * 4;
                #pragma unroll
                for (int nt = 0; nt < 4; ++nt) {
                    int pxl = nt * 16 + ln;
                    short4v pk;
                    pk[0] = (short)f2b(fmaxf(acc2[mt][nt][0] + b2r[mt][0], 0.f));
                    pk[1] = (short)f2b(fmaxf(acc2[mt][nt][1] + b2r[mt][1], 0.f));
                    pk[2] = (short)f2b(fmaxf(acc2[mt][nt][2] + b2r[mt][2], 0.f));
                    pk[3] = (short)f2b(fmaxf(acc2[mt][nt][3] + b2r[mt][3], 0.f));
                    *(short4v*)&h2s[chk * 512 + pxl * 8 + pos] = pk;
                }
            }
        }
        __syncthreads();   // C: h2s ready
        // ---- layer 3: wave computes 3 m-groups x 1 n-half from resident Ws
        float4v acc[3][2] = {};
        {
            const int r0l = mb * 16 + ln;
            const int swz = (r0l & 7) << 4;
            const char* Wb = (const char*)Ws;
            #pragma unroll
            for (int kc = 0; kc < 8; ++kc) {
                short8 a0 = *(const short8*)(Wb + (((r0l      ) * 512 + kc * 64 + lk * 2) ^ swz));
                short8 a1 = *(const short8*)(Wb + (((r0l +  64) * 512 + kc * 64 + lk * 2) ^ swz));
                short8 a2 = *(const short8*)(Wb + (((r0l + 128) * 512 + kc * 64 + lk * 2) ^ swz));
                #pragma unroll
                for (int ni = 0; ni < 2; ++ni) {
                    int nt = nh * 2 + ni;
                    short8 b = *(const short8*)&h2s[(kc * 4 + lkg) * 512 + (nt * 16 + ln) * 8];
                    acc[0][ni] = __builtin_amdgcn_mfma_f32_16x16x32_bf16(a0, b, acc[0][ni], 0, 0, 0);
                    acc[1][ni] = __builtin_amdgcn_mfma_f32_16x16x32_bf16(a1, b, acc[1][ni], 0, 0, 0);
                    acc[2][ni] = __builtin_amdgcn_mfma_f32_16x16x32_bf16(a2, b, acc[2][ni], 0, 0, 0);
                }
            }
        }
        // ---- epilogue: bias + direct register stores (no LDS transpose, no barrier;
        //      stores drain lazily at A(t+1))
        #pragma unroll
        for (int s = 0; s < 3; ++s) {
            const int tr0 = (mb + s * 4) * 16 + lkg * 4;
            #pragma unroll
            for (int r = 0; r < 4; ++r) {
                const size_t rowoff = (size_t)(obase + tr0 + r) * NPIX + px0;
                #pragma unroll
                for (int ni = 0; ni < 2; ++ni) {
                    int px = nh * 32 + ni * 16 + ln;
                    outp[rowoff + px] = f2b(acc[s][ni][r] + b3r[s][r]);
                }
            }
        }
        p0 = np0; p1 = np1; p2 = np2;
    }
}

// ---------------------------------------------------------------- bf16 MFMA 3x3 conv, 4-row tiles
// R8: replaces the 2-row template<4> for the two 64->64 convs.
//  - 4 output rows/block (grid 288 = 3 xt x 48 yg x 2 b; all resident at 2 blocks/CU,
//    2 waves/SIMD vs 1 before): 6-row halo stage + 72-VGPR Wr amortize over 2x rows.
//  - staged-row-major loop: each B fragment (1 KB ds_read_b128) is read ONCE and fed to
//    every output row using it (up to 3 MFMAs/read): 144 reads for 288 MFMAs vs 1:1
//    before -> LDS read volume halved.
__global__ __launch_bounds__(256, 2) void conv3x3_mfma4(
    const unsigned short* __restrict__ act, const unsigned short* __restrict__ wgt,
    const float* __restrict__ bias, unsigned short* __restrict__ out,
    int relu)
{
    constexpr int SP = 72;
    __shared__ unsigned short Bs[6 * 66 * SP];   // 57024 B -> 2 blocks/CU
    const int tid = threadIdx.x;
    int bx = blockIdx.x;
    const int xt = bx % 3; bx /= 3;
    const int yg = bx % 48; const int b = bx / 48;
    const int y0 = yg * 4;
    const int x0 = xt * 64;
    const size_t actb = (size_t)b * NPIX * 64;
    const int w = tid >> 6, l = tid & 63;
    const int ln = l & 15, lkg = l >> 4, lk = lkg * 8;
    const int mt = w;                             // wave -> 16-oc group
    short8 Wr[9][2];
    #pragma unroll
    for (int t = 0; t < 9; ++t)
        #pragma unroll
        for (int hh = 0; hh < 2; ++hh)
            Wr[t][hh] = *(const short8*)&wgt[((size_t)t * 64 + mt * 16 + ln) * 64 + hh * 32 + lk];
    for (int s = tid; s < 396; s += 256) {
        int r = s / 66, i = s % 66;
        int yy = y0 + r - 1, xx = x0 + i - 1;
        unsigned short* dst = &Bs[(r * 66 + i) * SP];
        if (yy >= 0 && yy < 192 && xx >= 0 && xx < 192) {
            const unsigned short* src = &act[actb + (size_t)(yy * 192 + xx) * 64];
            #pragma unroll
            for (int j = 0; j < 8; ++j) *(short8*)(dst + j * 8) = *(const short8*)(src + j * 8);
        } else {
            short8 z = {};
            #pragma unroll
            for (int j = 0; j < 8; ++j) *(short8*)(dst + j * 8) = z;
        }
    }
    __syncthreads();
    float4v acc[4][4] = {};
    #pragma unroll
    for (int rp = 0; rp < 6; ++rp) {              // staged row
        #pragma unroll
        for (int dx = 0; dx < 3; ++dx) {
            #pragma unroll
            for (int hh = 0; hh < 2; ++hh) {
                #pragma unroll
                for (int n = 0; n < 4; ++n) {
                    int slot = rp * 66 + n * 16 + ln + dx;
                    short8 bf = *(const short8*)&Bs[slot * SP + hh * 32 + lk];
                    #pragma unroll
                    for (int o = 0; o < 4; ++o) {
                        int r = rp - o;           // tap row for output row o
                        if (r < 0 || r > 2) continue;
                        acc[o][n] = __builtin_amdgcn_mfma_f32_16x16x32_bf16(Wr[r * 3 + dx][hh], bf, acc[o][n], 0, 0, 0);
                    }
                }
            }
        }
    }
    #pragma unroll
    for (int o = 0; o < 4; ++o) {
        #pragma unroll
        for (int n = 0; n < 4; ++n) {
            int px = (y0 + o) * 192 + x0 + n * 16 + ln;
            int oc = mt * 16 + lkg * 4;
            float v0 = acc[o][n][0] + bias[oc + 0];
            float v1 = acc[o][n][1] + bias[oc + 1];
            float v2 = acc[o][n][2] + bias[oc + 2];
            float v3 = acc[o][n][3] + bias[oc + 3];
            if (relu) { v0 = fmaxf(v0, 0.f); v1 = fmaxf(v1, 0.f); v2 = fmaxf(v2, 0.f); v3 = fmaxf(v3, 0.f); }
            uint2 pk;
            pk.x = (unsigned int)f2b(v0) | (((unsigned int)f2b(v1)) << 16);
            pk.y = (unsigned int)f2b(v2) | (((unsigned int)f2b(v3)) << 16);
            *(uint2*)&out[((size_t)b * NPIX + px) * 64 + oc] = pk;
        }
    }
}

// ---------------------------------------------------------------- bf16 MFMA 3x3 conv, 2-row tiles (MT=1 sigma conv)
template<int MT>
__global__ __launch_bounds__(256) void conv3x3_mfma(
    const unsigned short* __restrict__ act, const unsigned short* __restrict__ wgt,
    const float* __restrict__ bias, unsigned short* __restrict__ out,
    int relu)
{
    constexpr int SP = 72;
    constexpr int OCP = MT * 16;
    __shared__ unsigned short Bs[4 * 66 * SP];   // 38016 B
    const int tid = threadIdx.x;
    int bx = blockIdx.x;
    const int xt = bx % 3; bx /= 3;
    const int yg = bx % 96; const int b = bx / 96;
    const int y0 = yg * 2;
    const int x0 = xt * 64;
    const size_t actb = (size_t)b * NPIX * 64;
    const int w = tid >> 6, l = tid & 63;
    const int ln = l & 15, lkg = l >> 4, lk = lkg * 8;
    const int mt = (MT == 4) ? w : 0;
    short8 Wr[9][2];
    #pragma unroll
    for (int t = 0; t < 9; ++t)
        #pragma unroll
        for (int hh = 0; hh < 2; ++hh)
            Wr[t][hh] = *(const short8*)&wgt[((size_t)t * OCP + mt * 16 + ln) * 64 + hh * 32 + lk];
    for (int s = tid; s < 264; s += 256) {
        int r = s / 66, i = s % 66;
        int yy = y0 + r - 1, xx = x0 + i - 1;
        unsigned short* dst = &Bs[(r * 66 + i) * SP];
        if (yy >= 0 && yy < 192 && xx >= 0 && xx < 192) {
            const unsigned short* src = &act[actb + (size_t)(yy * 192 + xx) * 64];
            #pragma unroll
            for (int j = 0; j < 8; ++j) *(short8*)(dst + j * 8) = *(const short8*)(src + j * 8);
        } else {
            short8 z = {};
            #pragma unroll
            for (int j = 0; j < 8; ++j) *(short8*)(dst + j * 8) = z;
        }
    }
    __syncthreads();
    const int NT = (MT == 4) ? 4 : 1;
    const int ntb = (MT == 4) ? 0 : w;
    float4v acc[2][4] = {};
    #pragma unroll
    for (int t = 0; t < 9; ++t) {
        const int r = t / 3, dx = t % 3;
        #pragma unroll
        for (int hh = 0; hh < 2; ++hh) {
            #pragma unroll
            for (int o = 0; o < 2; ++o) {
                #pragma unroll
                for (int n = 0; n < 4; ++n) {
                    if (n >= NT) break;
                    int slot = (o + r) * 66 + (ntb + n) * 16 + ln + dx;
                    short8 bf = *(const short8*)&Bs[slot * SP + hh * 32 + lk];
                    acc[o][n] = __builtin_amdgcn_mfma_f32_16x16x32_bf16(Wr[t][hh], bf, acc[o][n], 0, 0, 0);
                }
            }
        }
    }
    #pragma unroll
    for (int o = 0; o < 2; ++o) {
        #pragma unroll
        for (int n = 0; n < 4; ++n) {
            if (n >= NT) break;
            int px = (y0 + o) * 192 + x0 + (ntb + n) * 16 + ln;
            if (MT == 4) {
                int oc = mt * 16 + lkg * 4;
                float v0 = acc[o][n][0] + bias[oc + 0];
                float v1 = acc[o][n][1] + bias[oc + 1];
                float v2 = acc[o][n][2] + bias[oc + 2];
                float v3 = acc[o][n][3] + bias[oc + 3];
                if (relu) { v0 = fmaxf(v0, 0.f); v1 = fmaxf(v1, 0.f); v2 = fmaxf(v2, 0.f); v3 = fmaxf(v3, 0.f); }
                uint2 pk;
                pk.x = (unsigned int)f2b(v0) | (((unsigned int)f2b(v1)) << 16);
                pk.y = (unsigned int)f2b(v2) | (((unsigned int)f2b(v3)) << 16);
                *(uint2*)&out[((size_t)b * NPIX + px) * 64 + oc] = pk;
            } else if (lkg == 0) {
                float v0 = acc[o][n][0] + bias[0];
                float v1 = acc[o][n][1] + bias[1];
                out[((size_t)b * 2 + 0) * NPIX + px] = f2b(v0);
                out[((size_t)b * 2 + 1) * NPIX + px] = f2b(v1);
            }
        }
    }
}

// ---------------------------------------------------------------- mean: single-plane LDS, sequential b
// LDS 20.4 KB -> 7 blocks/CU. b-invariant softmax weights precomputed in registers.
#define PLSZ 10192   // 98*104
__global__ __launch_bounds__(256) void mean_k(
    const unsigned short* __restrict__ xb, const int* __restrict__ imy, const int* __restrict__ imx,
    const unsigned short* __restrict__ dw, unsigned short* __restrict__ mean_cm)
{
    __shared__ unsigned short pl[PLSZ];
    const int c = blockIdx.y;
    const int px0 = blockIdx.x * 1024;
    const int tid = threadIdx.x;
    {   // zero once; borders stay zero across both stages (restage touches interior only)
        short8 z = {};
        short8* pf = (short8*)pl;
        for (int i = tid; i < PLSZ / 8; i += 256) pf[i] = z;
    }
    float wk[4][9];
    int base[4];
    #pragma unroll
    for (int q = 0; q < 4; ++q) {
        int px = px0 + q * 256 + tid;
        base[q] = imy[px] * 104 + imx[px] + 3;
        float d[9];
        #pragma unroll
        for (int k = 0; k < 9; ++k) d[k] = b2f(dw[(size_t)(c * 9 + k) * NPIX + px]);
        float m = d[0];
        #pragma unroll
        for (int k = 1; k < 9; ++k) m = fmaxf(m, d[k]);
        float s = 0.f;
        #pragma unroll
        for (int k = 0; k < 9; ++k) { wk[q][k] = __expf(d[k] - m); s += wk[q][k]; }
        float inv = 1.f / s;
        #pragma unroll
        for (int k = 0; k < 9; ++k) wk[q][k] *= inv;
    }
    #pragma unroll
    for (int b = 0; b < 2; ++b) {
        __syncthreads();   // zero done (b=0) / prior reads done (b=1)
        const unsigned short* xp = xb + (size_t)(b * 64 + c) * 9216;
        for (int i = tid; i < 96 * 12; i += 256) {
            int row = i / 12, ch = i % 12;
            const short4v* src = (const short4v*)&xp[row * 96 + ch * 8];
            unsigned short* dd = &pl[(row + 1) * 104 + 4 + ch * 8];
            *(short4v*)dd = src[0];
            *(short4v*)(dd + 4) = src[1];
        }
        __syncthreads();
        #pragma unroll
        for (int q = 0; q < 4; ++q) {
            int px = px0 + q * 256 + tid;
            float a = 0.f;
            #pragma unroll
            for (int k = 0; k < 9; ++k)
                a += wk[q][k] * b2f(pl[base[q] + (k / 3) * 104 + (k % 3)]);
            mean_cm[(size_t)(b * 64 + c) * NPIX + px] = f2b(a);
        }
    }
}

// ---------------------------------------------------------------- transpose [2][64][NPIX] -> [2][NPIX][64]
__global__ __launch_bounds__(256) void tr_k(
    const unsigned short* __restrict__ in, unsigned short* __restrict__ out)
{
    __shared__ unsigned short T[64 * 68];
    int px0 = blockIdx.x * 64;
    int b = blockIdx.y;
    int tid = threadIdx.x;
    for (int i = tid; i < 4096; i += 256) {
        int c = i >> 6, p = i & 63;
        T[p * 68 + c] = in[(size_t)(b * 64 + c) * NPIX + px0 + p];
    }
    __syncthreads();
    for (int i = tid; i < 4096; i += 256) {
        int p = i >> 6, c = i & 63;
        out[((size_t)b * NPIX + px0 + p) * 64 + c] = T[p * 68 + c];
    }
}

// ---------------------------------------------------------------- xa: single-plane LDS, sequential b
__global__ __launch_bounds__(256) void xa_k(
    const unsigned short* __restrict__ xb, const int* __restrict__ imy, const int* __restrict__ imx,
    const unsigned short* __restrict__ dw, const unsigned short* __restrict__ mean_cm,
    const unsigned short* __restrict__ sigma, unsigned short* __restrict__ xab)
{
    __shared__ unsigned short pl[PLSZ];
    const int c = blockIdx.y;
    const int px0 = blockIdx.x * 1024;
    const int tid = threadIdx.x;
    {
        short8 z = {};
        short8* pf = (short8*)pl;
        for (int i = tid; i < PLSZ / 8; i += 256) pf[i] = z;
    }
    float d[4][9];
    int base[4];
    #pragma unroll
    for (int q = 0; q < 4; ++q) {
        int px = px0 + q * 256 + tid;
        base[q] = imy[px] * 104 + imx[px] + 3;
        #pragma unroll
        for (int k = 0; k < 9; ++k) d[q][k] = b2f(dw[(size_t)(c * 9 + k) * NPIX + px]);
    }
    #pragma unroll
    for (int b = 0; b < 2; ++b) {
        __syncthreads();
        const unsigned short* xp = xb + (size_t)(b * 64 + c) * 9216;
        for (int i = tid; i < 96 * 12; i += 256) {
            int row = i / 12, ch = i % 12;
            const short4v* src = (const short4v*)&xp[row * 96 + ch * 8];
            unsigned short* dd = &pl[(row + 1) * 104 + 4 + ch * 8];
            *(short4v*)dd = src[0];
            *(short4v*)(dd + 4) = src[1];
        }
        __syncthreads();
        #pragma unroll
        for (int q = 0; q < 4; ++q) {
            int px = px0 + q * 256 + tid;
            float mn = b2f(mean_cm[(size_t)(b * 64 + c) * NPIX + px]);
            float sd = b2f(sigma[((size_t)b * 2 + 0) * NPIX + px]);
            float sr = b2f(sigma[((size_t)b * 2 + 1) * NPIX + px]);
            float h[9], bw[9];
            #pragma unroll
            for (int k = 0; k < 9; ++k) {
                h[k] = b2f(pl[base[q] + (k / 3) * 104 + (k % 3)]);
                bw[k] = sd * d[q][k] + sr * fabsf(h[k] - mn);
            }
            float m = bw[0];
            #pragma unroll
            for (int k = 1; k < 9; ++k) m = fmaxf(m, bw[k]);
            float s = 0.f, a = 0.f;
            #pragma unroll
            for (int k = 0; k < 9; ++k) { float e = __expf(bw[k] - m); s += e; a += e * h[k]; }
            xab[(size_t)(b * 64 + c) * NPIX + px] = f2b(a / s);
        }
    }
}

// ---------------------------------------------------------------- fused einsum: block = 64 px, 4 c-quarters
__global__ __launch_bounds__(256) void einsum_k(
    const unsigned short* __restrict__ xab, const unsigned short* __restrict__ pw,
    float* __restrict__ out)
{
    __shared__ float red[3][4][64];
    const int tid = threadIdx.x;
    const int pxl = tid & 63, cq = tid >> 6;
    const int px = blockIdx.x * 64 + pxl;
    const int b = blockIdx.y;
    float a0 = 0.f, a1 = 0.f, a2 = 0.f;
    #pragma unroll
    for (int ci = 0; ci < 16; ++ci) {
        int c = cq * 16 + ci;
        float v = b2f(xab[(size_t)(b * 64 + c) * NPIX + px]);
        a0 += v * b2f(pw[(size_t)(c * 3 + 0) * NPIX + px]);
        a1 += v * b2f(pw[(size_t)(c * 3 + 1) * NPIX + px]);
        a2 += v * b2f(pw[(size_t)(c * 3 + 2) * NPIX + px]);
    }
    red[0][cq][pxl] = a0;
    red[1][cq][pxl] = a1;
    red[2][cq][pxl] = a2;
    __syncthreads();
    if (cq < 3) {
        float s = red[cq][0][pxl] + red[cq][1][pxl] + red[cq][2][pxl] + red[cq][3][pxl];
        out[((size_t)b * 3 + cq) * NPIX + px] = s;
    }
}

extern "C" void kernel_launch(void* const* d_in, const int* in_sizes, int n_in,
                              void* d_out, int out_size, void* d_ws, size_t ws_size,
                              hipStream_t stream)
{
    (void)in_sizes; (void)n_in; (void)out_size; (void)ws_size;
    const float* x      = (const float*)d_in[0];
    const float* pose   = (const float*)d_in[1];
    const int*   imy    = (const int*)d_in[2];
    const int*   imx    = (const int*)d_in[3];
    const float* sig_w1 = (const float*)d_in[4];
    const float* sig_b1 = (const float*)d_in[5];
    const float* sig_w2 = (const float*)d_in[6];
    const float* sig_b2 = (const float*)d_in[7];
    const float* sig_w3 = (const float*)d_in[8];
    const float* sig_b3 = (const float*)d_in[9];
    const float* dw_w1  = (const float*)d_in[10];
    const float* dw_b1  = (const float*)d_in[11];
    const float* dw_w2  = (const float*)d_in[12];
    const float* dw_b2  = (const float*)d_in[13];
    const float* dw_w3  = (const float*)d_in[14];
    const float* dw_b3  = (const float*)d_in[15];
    const float* pw_w1  = (const float*)d_in[16];
    const float* pw_b1  = (const float*)d_in[17];
    const float* pw_w2  = (const float*)d_in[18];
    const float* pw_b2  = (const float*)d_in[19];
    const float* pw_w3  = (const float*)d_in[20];
    const float* pw_b3  = (const float*)d_in[21];
    float* out = (float*)d_out;

    unsigned short* ws = (unsigned short*)d_ws;
    size_t off = 0;
    unsigned short* wb      = ws + off; off += WB_TOTAL;
    unsigned short* xb16    = ws + off; off += (size_t)XCAST_N;
    unsigned short* dwbuf   = ws + off; off += (size_t)576 * NPIX;      // plane-major
    unsigned short* pwbuf   = ws + off; off += (size_t)192 * NPIX;      // plane-major
    unsigned short* mean_cm = ws + off; off += (size_t)2 * 64 * NPIX;
    unsigned short* mean_pm = ws + off; off += (size_t)2 * NPIX * 64;
    unsigned short* s1      = ws + off; off += (size_t)2 * NPIX * 64;
    unsigned short* s2      = ws + off; off += (size_t)2 * NPIX * 64;
    unsigned short* sigma   = ws + off; off += (size_t)2 * 2 * NPIX;
    unsigned short* xab     = ws + off; off += (size_t)2 * 64 * NPIX;

    unsigned short* w_dw2 = wb + 0;
    unsigned short* w_pw2 = wb + 16384;
    unsigned short* w_33  = wb + 32768;   // combined [768][256]
    unsigned short* w_s1t = wb + 229376;
    unsigned short* w_s2t = wb + 266240;
    unsigned short* w_s3t = wb + 303104;

    dim3 blk(256);
    prep_all<<<dim3((WB_TOTAL + XCAST_N + 255) / 256), blk, 0, stream>>>(
        dw_w2, dw_w3, pw_w2, pw_w3, sig_w1, sig_w2, sig_w3, wb, x, xb16);
    mlp_fused<<<dim3(64, 4), dim3(512), 0, stream>>>(
        pose, dw_w1, dw_b1, pw_w1, pw_b1, w_dw2, w_pw2, dw_b2, pw_b2,
        w_33, dw_b3, pw_b3, dwbuf, pwbuf);
    mean_k<<<dim3(36, 64), blk, 0, stream>>>(xb16, imy, imx, dwbuf, mean_cm);
    tr_k<<<dim3(576, 2), blk, 0, stream>>>(mean_cm, mean_pm);
    conv3x3_mfma4<<<dim3(288), blk, 0, stream>>>(mean_pm, w_s1t, sig_b1, s1, 1);
    conv3x3_mfma4<<<dim3(288), blk, 0, stream>>>(s1,      w_s2t, sig_b2, s2, 1);
    conv3x3_mfma<1><<<dim3(576), blk, 0, stream>>>(s2,     w_s3t, sig_b3, sigma, 0);
    xa_k<<<dim3(36, 64), blk, 0, stream>>>(xb16, imy, imx, dwbuf, mean_cm, sigma, xab);
    einsum_k<<<dim3(576, 2), blk, 0, stream>>>(xab, pwbuf, out);
}